// Round 11
// baseline (423.798 us; speedup 1.0000x reference)
//
#include <hip/hip_runtime.h>
#include <stdint.h>

#define EMB 64
#define BN_EPS 1e-5f
#define CHUNK 4096         // edges per enc-prep/scatter chunk
#define TS 68              // fp32 LDS tile stride: 2-way max bank aliasing

typedef short bfrag __attribute__((ext_vector_type(8)));   // 8 bf16 = 4 VGPRs
typedef float f32x4 __attribute__((ext_vector_type(4)));

#define IN_F32    0
#define IN_BF16   1
#define IN_BF16BN 2

struct SMM {
  float tb[64 * TS];            // 17408 B
  float st[128];                // 512 B
  float scs[EMB], shs[EMB];     // 512 B
  unsigned short wb[4096];      // 8192 B (encoder weights, enc path only)
};

__device__ __forceinline__ unsigned short f2b(float x) {
  unsigned u = __float_as_uint(x);
  u += 0x7FFFu + ((u >> 16) & 1u);   // round-to-nearest-even
  return (unsigned short)(u >> 16);
}
__device__ __forceinline__ float b2f(unsigned short v) {
  return __uint_as_float(((unsigned)v) << 16);
}

// ---------------- 512-thr MFMA tile core (encoder only) --------------------
__device__ __forceinline__ void enc_tile(SMM& sm, int tile,
    const float* x, const float* aewf, const float* bias,
    unsigned short* out16, int N) {
  const int tid = threadIdx.x;       // 0..511
  const int lane = tid & 63;
  const int wv = tid >> 6;           // 0..7
  const int r = wv >> 1;             // row-tile 0..3
  const int c0 = (wv & 1) * 2;       // col-tile pair
  const int m = lane & 15;
  const int quad = lane >> 4;
  const int node0 = tile * 64;

  // self-convert encoder weights: wb[j*64+k] = bf16(ae_w[k][j])
#pragma unroll
  for (int it = 0; it < 8; it++) {
    int idx = it * 512 + tid;
    int j = idx >> 6, k = idx & 63;
    sm.wb[idx] = f2b(aewf[k * EMB + j]);
  }
  __syncthreads();

  bfrag a0 = {0, 0, 0, 0, 0, 0, 0, 0}, a1 = {0, 0, 0, 0, 0, 0, 0, 0};
  const int arow = node0 + r * 16 + m;
  if (arow < N) {
    const float4* af4 = (const float4*)(x + (size_t)arow * EMB + quad * 8);
    float4 f0 = af4[0], f1 = af4[1];     // feats quad*8 .. quad*8+7
    float4 f2 = af4[8], f3 = af4[9];     // feats 32+quad*8 ..
    a0[0] = (short)f2b(f0.x); a0[1] = (short)f2b(f0.y);
    a0[2] = (short)f2b(f0.z); a0[3] = (short)f2b(f0.w);
    a0[4] = (short)f2b(f1.x); a0[5] = (short)f2b(f1.y);
    a0[6] = (short)f2b(f1.z); a0[7] = (short)f2b(f1.w);
    a1[0] = (short)f2b(f2.x); a1[1] = (short)f2b(f2.y);
    a1[2] = (short)f2b(f2.z); a1[3] = (short)f2b(f2.w);
    a1[4] = (short)f2b(f3.x); a1[5] = (short)f2b(f3.y);
    a1[6] = (short)f2b(f3.z); a1[7] = (short)f2b(f3.w);
  }
  f32x4 zz[2];
#pragma unroll
  for (int cc = 0; cc < 2; cc++) {
    const int c = c0 + cc;
    const unsigned short* bb = &sm.wb[(c * 16 + m) * EMB + quad * 8];
    bfrag b0 = *(const bfrag*)bb;
    bfrag b1 = *(const bfrag*)(bb + 32);
    f32x4 z = {0.f, 0.f, 0.f, 0.f};
    z = __builtin_amdgcn_mfma_f32_16x16x32_bf16(a0, b0, z, 0, 0, 0);
    z = __builtin_amdgcn_mfma_f32_16x16x32_bf16(a1, b1, z, 0, 0, 0);
    zz[cc] = z;
  }
#pragma unroll
  for (int cc = 0; cc < 2; cc++) {
    const int c = c0 + cc;
    float bj = bias[c * 16 + m];
#pragma unroll
    for (int reg = 0; reg < 4; reg++) {
      int row = r * 16 + quad * 4 + reg;
      float v = (node0 + row < N) ? (zz[cc][reg] + bj) : 0.f;
      sm.tb[row * TS + c * 16 + m] = v;
    }
  }
  __syncthreads();
  ushort4* o4 = (ushort4*)(out16 + (size_t)node0 * EMB);
#pragma unroll
  for (int it = 0; it < 2; it++) {
    int flat4 = it * 512 + tid;
    int nsub = flat4 >> 4;
    int c4 = flat4 & 15;
    if (node0 + nsub < N) {
      const float* s4 = sm.tb + nsub * TS + c4 * 4;
      ushort4 o;
      o.x = f2b(s4[0]); o.y = f2b(s4[1]);
      o.z = f2b(s4[2]); o.w = f2b(s4[3]);
      o4[flat4] = o;
    }
  }
}

// ---- dispatch 2: encoder tiles + {W transpose, stats zero, node degrees} --
// (counts pre-zeroed by hipMemsetAsync; per-node degree via global atomics)
__global__ void __launch_bounds__(512) k_enc_prep(
        const float* __restrict__ x, const float* __restrict__ ae_w,
        const float* __restrict__ ae_b,
        const float* __restrict__ W1, const float* __restrict__ W2,
        unsigned short* __restrict__ Wt16, int* __restrict__ counts,
        float* __restrict__ stats, const int* __restrict__ ei,
        unsigned short* __restrict__ hb16,
        int E, int L, int nstats, int ntiles, int nchunks, int N) {
  __shared__ SMM sm;
  if ((int)blockIdx.x < ntiles) {
    enc_tile(sm, blockIdx.x, x, ae_w, ae_b, hb16, N);
    return;
  }
  const int pb = blockIdx.x - ntiles;   // chunk id 0..nchunks-1
  const int tid = threadIdx.x;
  const int nw2 = 2 * L * EMB * EMB;
  for (int gid = pb * 512 + tid; gid < nw2; gid += nchunks * 512) {
    int mI = gid >> 12;
    int j = (gid >> 6) & 63;
    int k = gid & 63;
    const float* src = (mI < L) ? W1 + (size_t)mI * EMB * EMB
                                : W2 + (size_t)(mI - L) * EMB * EMB;
    Wt16[EMB * EMB + gid] = f2b(src[k * EMB + j]);
  }
  for (int i = pb * 512 + tid; i < nstats; i += nchunks * 512) stats[i] = 0.0f;
  // per-node degree histogram (global atomics, low contention)
  const int c0 = pb * CHUNK;
  const int cend = min(c0 + CHUNK, E);
  for (int e = c0 + tid; e < cend; e += 512)
    atomicAdd(&counts[ei[E + e]], 1);
}

// ---- dispatch 3: exact per-node CSR offsets --------------------------------
// Every block redundantly computes all 256 bucket totals from counts
// (8-deep unrolled, L2-hot), scans them, then LDS-scans its own bucket's
// 256 node degrees -> rowst; zeroes cur. counts padded to 256*256 ints.
__global__ void __launch_bounds__(256) k_scan(
        const int* __restrict__ counts, int* __restrict__ rowst,
        int* __restrict__ cur) {
  __shared__ int a[256];
  const int t = threadIdx.x;
  const int b = blockIdx.x;
  int tot = 0;
  const int* cb = counts + t * 256;
#pragma unroll 8
  for (int i = 0; i < 256; i++) tot += cb[i];
  a[t] = tot;
  __syncthreads();
  for (int off = 1; off < 256; off <<= 1) {
    int x = (t >= off) ? a[t - off] : 0;
    __syncthreads();
    a[t] += x;
    __syncthreads();
  }
  const int bucketBase = (b == 0) ? 0 : a[b - 1];
  __syncthreads();
  int c = counts[b * 256 + t];
  a[t] = c;
  __syncthreads();
  for (int off = 1; off < 256; off <<= 1) {
    int x = (t >= off) ? a[t - off] : 0;
    __syncthreads();
    a[t] += x;
    __syncthreads();
  }
  int excl = a[t] - c;
  rowst[b * 256 + t] = bucketBase + excl;
  cur[b * 256 + t] = 0;
}

// ---- dispatch 4: one-pass direct edge scatter ------------------------------
__global__ void __launch_bounds__(256) k_scatter(
        const int* __restrict__ ei, const float* __restrict__ ew,
        const int* __restrict__ rowst, int* __restrict__ cur,
        int2* __restrict__ pairs, int E) {
  const int t = threadIdx.x;
  const int c0 = blockIdx.x * CHUNK;
#pragma unroll 4
  for (int i = 0; i < 16; i++) {
    int e = c0 + i * 256 + t;
    if (e < E) {
      int d = ei[E + e];
      int pos = rowst[d] + atomicAdd(&cur[d], 1);
      pairs[pos] = make_int2(ei[e], __float_as_int(ew[e]));
    }
  }
}

// ---- layer-0 aggregation: dword-packed gather, 2 nodes interleaved --------
__global__ void k_agg(const unsigned short* __restrict__ hb,
                      const int* __restrict__ rowst,
                      const int* __restrict__ counts, const int2* __restrict__ pairs,
                      unsigned short* __restrict__ out16, int N) {
  const int lane = threadIdx.x & 63;
  const int half = lane >> 5;          // 0: even slots, 1: odd slots
  const int col = lane & 31;           // dword col -> features 2col, 2col+1
  int wave = (blockIdx.x * blockDim.x + threadIdx.x) >> 6;
  const int nwaves = (gridDim.x * blockDim.x) >> 6;
  for (int nA = wave; nA < N; nA += 2 * nwaves) {
    const int nB = nA + nwaves;
    const int uA = __builtin_amdgcn_readfirstlane(nA);
    const int uB = __builtin_amdgcn_readfirstlane(nB);
    const bool hasB = uB < N;
    int sA = rowst[uA], eA = sA + counts[uA];
    int sB = 0, eB = 0;
    if (hasB) { sB = rowst[uB]; eB = sB + counts[uB]; }
    float a0A[4] = {0, 0, 0, 0}, a1A[4] = {0, 0, 0, 0};
    float a0B[4] = {0, 0, 0, 0}, a1B[4] = {0, 0, 0, 0};
    for (int xA = sA, xB = sB; (xA < eA) | (xB < eB); xA += 8, xB += 8) {
      int2 pA[8], pB[8];
#pragma unroll
      for (int k = 0; k < 8; k++) {
        int ia = xA + k;
        pA[k] = pairs[ia < eA ? ia : 0];
      }
#pragma unroll
      for (int k = 0; k < 8; k++) {
        int ib = xB + k;
        pB[k] = pairs[ib < eB ? ib : 0];
      }
#pragma unroll
      for (int j = 0; j < 4; j++) {
        int2 pp = half ? pA[2 * j + 1] : pA[2 * j];
        bool ok = (xA + 2 * j + half) < eA;
        float w = ok ? __int_as_float(pp.y) : 0.f;
        unsigned v = *((const unsigned*)(hb + (size_t)pp.x * EMB) + col);
        a0A[j] = fmaf(w, b2f((unsigned short)(v & 0xFFFFu)), a0A[j]);
        a1A[j] = fmaf(w, b2f((unsigned short)(v >> 16)), a1A[j]);
      }
#pragma unroll
      for (int j = 0; j < 4; j++) {
        int2 pp = half ? pB[2 * j + 1] : pB[2 * j];
        bool ok = (xB + 2 * j + half) < eB;
        float w = ok ? __int_as_float(pp.y) : 0.f;
        unsigned v = *((const unsigned*)(hb + (size_t)pp.x * EMB) + col);
        a0B[j] = fmaf(w, b2f((unsigned short)(v & 0xFFFFu)), a0B[j]);
        a1B[j] = fmaf(w, b2f((unsigned short)(v >> 16)), a1B[j]);
      }
    }
    {
      float s0 = (a0A[0] + a0A[1]) + (a0A[2] + a0A[3]);
      float s1 = (a1A[0] + a1A[1]) + (a1A[2] + a1A[3]);
      s0 += __shfl_xor(s0, 32);
      s1 += __shfl_xor(s1, 32);
      float v0 = __shfl(s0, lane >> 1);
      float v1 = __shfl(s1, lane >> 1);
      float sum = ((lane & 1) ? v1 : v0) + b2f(hb[(size_t)uA * EMB + lane]);
      out16[(size_t)uA * EMB + lane] = f2b(sum);
    }
    if (hasB) {
      float s0 = (a0B[0] + a0B[1]) + (a0B[2] + a0B[3]);
      float s1 = (a1B[0] + a1B[1]) + (a1B[2] + a1B[3]);
      s0 += __shfl_xor(s0, 32);
      s1 += __shfl_xor(s1, 32);
      float v0 = __shfl(s0, lane >> 1);
      float v1 = __shfl(s1, lane >> 1);
      float sum = ((lane & 1) ? v1 : v0) + b2f(hb[(size_t)uB * EMB + lane]);
      out16[(size_t)uB * EMB + lane] = f2b(sum);
    }
  }
}

// ---- layers 1..: fused bnres + aggregation, 2 nodes interleaved -----------
__global__ void k_aggbn(const unsigned short* __restrict__ u16,
                        const unsigned short* __restrict__ hold,
                        const float* __restrict__ st,
                        const float* __restrict__ g, const float* __restrict__ be,
                        const int* __restrict__ rowst,
                        const int* __restrict__ counts,
                        const int2* __restrict__ pairs,
                        unsigned short* __restrict__ hnew,
                        unsigned short* __restrict__ out16,
                        float invN, int N) {
  __shared__ float scs[EMB], shs[EMB];
  const int tid = threadIdx.x;
  if (tid < EMB) {
    float s1 = 0.f, s2 = 0.f;
#pragma unroll
    for (int k = 0; k < 8; k++) {
      s1 += st[k * 128 + tid];
      s2 += st[k * 128 + 64 + tid];
    }
    float mu = s1 * invN;
    float va = fmaf(s2, invN, -mu * mu);
    float rs = rsqrtf(va + BN_EPS);
    float sc = rs * g[tid];
    scs[tid] = sc;
    shs[tid] = fmaf(-mu, sc, be[tid]);
  }
  __syncthreads();
  const int lane = tid & 63;
  const int half = lane >> 5;
  const int col = lane & 31;
  const float sc0 = scs[2 * col], sc1 = scs[2 * col + 1];
  const float sh0 = shs[2 * col], sh1 = shs[2 * col + 1];
  const float scl = scs[lane], shl = shs[lane];
  int wave = (blockIdx.x * blockDim.x + tid) >> 6;
  const int nwaves = (gridDim.x * blockDim.x) >> 6;
  for (int nA = wave; nA < N; nA += 2 * nwaves) {
    const int nB = nA + nwaves;
    const int uA = __builtin_amdgcn_readfirstlane(nA);
    const int uB = __builtin_amdgcn_readfirstlane(nB);
    const bool hasB = uB < N;
    int sA = rowst[uA], eA = sA + counts[uA];
    int sB = 0, eB = 0;
    if (hasB) { sB = rowst[uB]; eB = sB + counts[uB]; }
    // self rows: h_l at feature `lane`
    float hnA = fmaxf(0.f, fmaf(b2f(u16[(size_t)uA * EMB + lane]), scl, shl)) +
                b2f(hold[(size_t)uA * EMB + lane]);
    float hnB = 0.f;
    if (hasB)
      hnB = fmaxf(0.f, fmaf(b2f(u16[(size_t)uB * EMB + lane]), scl, shl)) +
            b2f(hold[(size_t)uB * EMB + lane]);
    float a0A[4] = {0, 0, 0, 0}, a1A[4] = {0, 0, 0, 0};
    float a0B[4] = {0, 0, 0, 0}, a1B[4] = {0, 0, 0, 0};
    for (int xA = sA, xB = sB; (xA < eA) | (xB < eB); xA += 8, xB += 8) {
      int2 pA[8], pB[8];
#pragma unroll
      for (int k = 0; k < 8; k++) {
        int ia = xA + k;
        pA[k] = pairs[ia < eA ? ia : 0];
      }
#pragma unroll
      for (int k = 0; k < 8; k++) {
        int ib = xB + k;
        pB[k] = pairs[ib < eB ? ib : 0];
      }
#pragma unroll
      for (int j = 0; j < 4; j++) {
        int2 p = half ? pA[2 * j + 1] : pA[2 * j];
        bool ok = (xA + 2 * j + half) < eA;
        float w = ok ? __int_as_float(p.y) : 0.f;
        const size_t base = (size_t)p.x * EMB;
        unsigned vu = *((const unsigned*)(u16 + base) + col);
        unsigned vh = *((const unsigned*)(hold + base) + col);
        float h0 = fmaxf(0.f, fmaf(b2f((unsigned short)(vu & 0xFFFFu)), sc0, sh0))
                   + b2f((unsigned short)(vh & 0xFFFFu));
        float h1 = fmaxf(0.f, fmaf(b2f((unsigned short)(vu >> 16)), sc1, sh1))
                   + b2f((unsigned short)(vh >> 16));
        a0A[j] = fmaf(w, h0, a0A[j]);
        a1A[j] = fmaf(w, h1, a1A[j]);
      }
#pragma unroll
      for (int j = 0; j < 4; j++) {
        int2 p = half ? pB[2 * j + 1] : pB[2 * j];
        bool ok = (xB + 2 * j + half) < eB;
        float w = ok ? __int_as_float(p.y) : 0.f;
        const size_t base = (size_t)p.x * EMB;
        unsigned vu = *((const unsigned*)(u16 + base) + col);
        unsigned vh = *((const unsigned*)(hold + base) + col);
        float h0 = fmaxf(0.f, fmaf(b2f((unsigned short)(vu & 0xFFFFu)), sc0, sh0))
                   + b2f((unsigned short)(vh & 0xFFFFu));
        float h1 = fmaxf(0.f, fmaf(b2f((unsigned short)(vu >> 16)), sc1, sh1))
                   + b2f((unsigned short)(vh >> 16));
        a0B[j] = fmaf(w, h0, a0B[j]);
        a1B[j] = fmaf(w, h1, a1B[j]);
      }
    }
    {
      float s0 = (a0A[0] + a0A[1]) + (a0A[2] + a0A[3]);
      float s1 = (a1A[0] + a1A[1]) + (a1A[2] + a1A[3]);
      s0 += __shfl_xor(s0, 32);
      s1 += __shfl_xor(s1, 32);
      float v0 = __shfl(s0, lane >> 1);
      float v1 = __shfl(s1, lane >> 1);
      float sum = ((lane & 1) ? v1 : v0) + hnA;
      out16[(size_t)uA * EMB + lane] = f2b(sum);
      hnew[(size_t)uA * EMB + lane] = f2b(hnA);
    }
    if (hasB) {
      float s0 = (a0B[0] + a0B[1]) + (a0B[2] + a0B[3]);
      float s1 = (a1B[0] + a1B[1]) + (a1B[2] + a1B[3]);
      s0 += __shfl_xor(s0, 32);
      s1 += __shfl_xor(s1, 32);
      float v0 = __shfl(s0, lane >> 1);
      float v1 = __shfl(s1, lane >> 1);
      float sum = ((lane & 1) ? v1 : v0) + hnB;
      out16[(size_t)uB * EMB + lane] = f2b(sum);
      hnew[(size_t)uB * EMB + lane] = f2b(hnB);
    }
  }
}

// ---------------- MFMA matmul: block = 64-node tile, 4 waves ---------------
template <int INMODE, bool DO_STATS>
__global__ void __launch_bounds__(256) k_mmx(
        const void* __restrict__ in_v, const unsigned short* __restrict__ Wt,
        const float* __restrict__ bias, const float* __restrict__ stats,
        const float* __restrict__ g, const float* __restrict__ be, float invN,
        unsigned short* __restrict__ out16, float* __restrict__ st_out, int N) {
  __shared__ float tb[64 * TS];
  __shared__ float st_part[128];
  __shared__ float scs[EMB], shs[EMB];
  const int tid = threadIdx.x;
  const int lane = tid & 63;
  const int wv = tid >> 6;
  const int node0 = blockIdx.x * 64;
  const int m = lane & 15;
  const int quad = lane >> 4;

  if (DO_STATS && tid < 128) st_part[tid] = 0.f;
  if (INMODE == IN_BF16BN) {
    if (tid < EMB) {
      float s1 = 0.f, s2 = 0.f;
#pragma unroll
      for (int k = 0; k < 8; k++) {
        s1 += stats[k * 128 + tid];
        s2 += stats[k * 128 + 64 + tid];
      }
      float mm = s1 * invN;
      float va = fmaf(s2, invN, -mm * mm);
      float rs = rsqrtf(va + BN_EPS);
      float sc = rs * g[tid];
      scs[tid] = sc;
      shs[tid] = fmaf(-mm, sc, be[tid]);
    }
    __syncthreads();
  }

  const int arow = node0 + wv * 16 + m;
  bfrag a0 = {0, 0, 0, 0, 0, 0, 0, 0}, a1 = {0, 0, 0, 0, 0, 0, 0, 0};
  if (arow < N) {
    if (INMODE == IN_BF16) {
      const unsigned short* ab =
          (const unsigned short*)in_v + (size_t)arow * EMB + quad * 8;
      a0 = *(const bfrag*)ab;
      a1 = *(const bfrag*)(ab + 32);
    } else if (INMODE == IN_BF16BN) {
      const unsigned short* ab =
          (const unsigned short*)in_v + (size_t)arow * EMB + quad * 8;
      bfrag r0 = *(const bfrag*)ab;
      bfrag r1 = *(const bfrag*)(ab + 32);
#pragma unroll
      for (int j = 0; j < 8; j++) {
        int k0 = quad * 8 + j;
        float v0 = b2f((unsigned short)r0[j]);
        float v1 = b2f((unsigned short)r1[j]);
        v0 = fmaxf(0.f, fmaf(v0, scs[k0], shs[k0]));
        v1 = fmaxf(0.f, fmaf(v1, scs[k0 + 32], shs[k0 + 32]));
        a0[j] = (short)f2b(v0);
        a1[j] = (short)f2b(v1);
      }
    }
  }

  const unsigned short* bb = Wt + (size_t)m * EMB + quad * 8;
  f32x4 acc[4];
#pragma unroll
  for (int c = 0; c < 4; c++) {
    bfrag b0 = *(const bfrag*)(bb + c * 16 * EMB);
    bfrag b1 = *(const bfrag*)(bb + c * 16 * EMB + 32);
    f32x4 z = {0.f, 0.f, 0.f, 0.f};
    z = __builtin_amdgcn_mfma_f32_16x16x32_bf16(a0, b0, z, 0, 0, 0);
    z = __builtin_amdgcn_mfma_f32_16x16x32_bf16(a1, b1, z, 0, 0, 0);
    acc[c] = z;
  }

#pragma unroll
  for (int c = 0; c < 4; c++) {
    float bj = bias[c * 16 + m];
#pragma unroll
    for (int r = 0; r < 4; r++) {
      int row = wv * 16 + quad * 4 + r;
      float v = (node0 + row < N) ? (acc[c][r] + bj) : 0.f;
      tb[row * TS + c * 16 + m] = v;
    }
  }
  __syncthreads();

  if (DO_STATS) {
    float ssum = 0.f, ssq = 0.f;
#pragma unroll
    for (int i = 0; i < 16; i++) {
      float v = tb[(wv * 16 + i) * TS + lane];
      ssum += v;
      ssq = fmaf(v, v, ssq);
    }
    atomicAdd(&st_part[lane], ssum);
    atomicAdd(&st_part[64 + lane], ssq);
  }

  ushort4* o4 = (ushort4*)(out16 + (size_t)node0 * EMB);
#pragma unroll
  for (int it = 0; it < 4; it++) {
    int flat4 = it * 256 + tid;
    int nsub = flat4 >> 4;
    int c4 = flat4 & 15;
    if (node0 + nsub < N) {
      const float* s4 = tb + nsub * TS + c4 * 4;
      ushort4 o;
      o.x = f2b(s4[0]); o.y = f2b(s4[1]);
      o.z = f2b(s4[2]); o.w = f2b(s4[3]);
      o4[flat4] = o;
    }
  }

  if (DO_STATS) {
    __syncthreads();
    if (tid < 128)
      atomicAdd(&st_out[((unsigned)blockIdx.x & 7u) * 128 + tid], st_part[tid]);
  }
}

// ---------------- final BN + relu + residual -> fp32 out -------------------
__global__ void k_bnres_last(const unsigned short* __restrict__ u16,
                             const float* __restrict__ st,
                             const float* __restrict__ g,
                             const float* __restrict__ be,
                             const unsigned short* __restrict__ hb16,
                             float* __restrict__ out32,
                             float invN, int total4) {
  __shared__ float scs[EMB], shs[EMB];
  const int tid = threadIdx.x;
  if (tid < EMB) {
    float s1 = 0.f, s2 = 0.f;
#pragma unroll
    for (int k = 0; k < 8; k++) {
      s1 += st[k * 128 + tid];
      s2 += st[k * 128 + 64 + tid];
    }
    float mm = s1 * invN;
    float va = fmaf(s2, invN, -mm * mm);
    float rs = rsqrtf(va + BN_EPS);
    float sc = rs * g[tid];
    scs[tid] = sc;
    shs[tid] = fmaf(-mm, sc, be[tid]);
  }
  __syncthreads();
  int stride = gridDim.x * blockDim.x;
  for (int i4 = blockIdx.x * blockDim.x + tid; i4 < total4; i4 += stride) {
    int c4 = i4 & 15;
    ushort4 uv = ((const ushort4*)u16)[i4];
    ushort4 hv = ((const ushort4*)hb16)[i4];
    float4 scv = *(const float4*)&scs[c4 * 4];
    float4 shv = *(const float4*)&shs[c4 * 4];
    float4 o;
    o.x = fmaxf(0.f, fmaf(b2f(uv.x), scv.x, shv.x)) + b2f(hv.x);
    o.y = fmaxf(0.f, fmaf(b2f(uv.y), scv.y, shv.y)) + b2f(hv.y);
    o.z = fmaxf(0.f, fmaf(b2f(uv.z), scv.z, shv.z)) + b2f(hv.z);
    o.w = fmaxf(0.f, fmaf(b2f(uv.w), scv.w, shv.w)) + b2f(hv.w);
    ((float4*)out32)[i4] = o;
  }
}

// ---------------- launcher ----------------
extern "C" void kernel_launch(void* const* d_in, const int* in_sizes, int n_in,
                              void* d_out, int out_size, void* d_ws, size_t ws_size,
                              hipStream_t stream) {
  const float* x     = (const float*)d_in[0];
  const int*   ei    = (const int*)d_in[1];
  const float* ew    = (const float*)d_in[3];
  const float* ae_w  = (const float*)d_in[4];
  const float* ae_b  = (const float*)d_in[5];
  const float* W1    = (const float*)d_in[6];
  const float* b1    = (const float*)d_in[7];
  const float* g1    = (const float*)d_in[8];
  const float* be1   = (const float*)d_in[9];
  const float* W2    = (const float*)d_in[10];
  const float* b2    = (const float*)d_in[11];
  const float* g_out = (const float*)d_in[12];
  const float* be_out= (const float*)d_in[13];

  const int N = in_sizes[0] / EMB;
  const int E = in_sizes[3];
  const int L = in_sizes[6] / (EMB * EMB);
  const float invN = 1.0f / (float)N;
  const int NBUCK = (N + 255) >> 8;
  const int nchunks = (E + CHUNK - 1) / CHUNK;

  uintptr_t p = (uintptr_t)d_ws;
  auto alloc = [&](size_t bytes) -> void* {
    p = (p + 255) & ~(uintptr_t)255;
    void* r = (void*)p;
    p += bytes;
    return r;
  };
  unsigned short* hbA  = (unsigned short*)alloc((size_t)N * EMB * 2); // h ping
  unsigned short* hbB  = (unsigned short*)alloc((size_t)N * EMB * 2); // h pong
  unsigned short* a16  = (unsigned short*)alloc((size_t)N * EMB * 2); // agg out
  unsigned short* t16  = (unsigned short*)alloc((size_t)N * EMB * 2); // t
  unsigned short* u16  = (unsigned short*)alloc((size_t)N * EMB * 2); // u (mm2)
  unsigned short* Wt16 = (unsigned short*)alloc((size_t)(1 + 2 * L) * EMB * EMB * 2);
  int*   counts= (int*)alloc((size_t)256 * 256 * 4);     // padded for k_scan
  int*   rowst = (int*)alloc((size_t)NBUCK * 256 * 4);
  int*   cur   = (int*)alloc((size_t)NBUCK * 256 * 4);
  int2*  pairs = (int2*)alloc((size_t)E * 8);
  float* stats = (float*)alloc((size_t)L * 2 * 8 * 128 * 4);
  (void)ws_size; (void)n_in; (void)out_size;

  const int ntiles = (N + 63) / 64;
  const int nstats = L * 2 * 8 * 128;

  // 1: zero padded degree array (must precede enc_prep's atomics)
  hipMemsetAsync(counts, 0, (size_t)256 * 256 * 4, stream);
  // 2: encoder tiles + {W transpose, stats zero, per-node degrees}
  hipLaunchKernelGGL(k_enc_prep, dim3(ntiles + nchunks), dim3(512), 0, stream,
                     x, ae_w, ae_b, W1, W2, Wt16, counts, stats, ei,
                     hbA, E, L, nstats, ntiles, nchunks, N);
  // 3: exact per-node CSR offsets (rowst) + cur=0
  hipLaunchKernelGGL(k_scan, dim3(NBUCK), dim3(256), 0, stream,
                     counts, rowst, cur);
  // 4: one-pass direct edge scatter -> pairs
  hipLaunchKernelGGL(k_scatter, dim3(nchunks), dim3(256), 0, stream,
                     ei, ew, rowst, cur, pairs, E);

  unsigned short* hcur = hbA;
  unsigned short* hnxt = hbB;
  for (int l = 0; l < L; l++) {
    float* stats1 = stats + (size_t)(l * 2 + 0) * 1024;
    float* stats2 = stats + (size_t)(l * 2 + 1) * 1024;

    if (l == 0) {
      hipLaunchKernelGGL(k_agg, dim3(2048), dim3(256), 0, stream,
                         hcur, rowst, counts, pairs, a16, N);
    } else {
      float* stats2p = stats + (size_t)((l - 1) * 2 + 1) * 1024;
      hipLaunchKernelGGL(k_aggbn, dim3(2048), dim3(256), 0, stream,
                         u16, hcur, stats2p, g_out + (size_t)(l - 1) * EMB,
                         be_out + (size_t)(l - 1) * EMB, rowst, counts, pairs,
                         hnxt, a16, invN, N);
      unsigned short* tmp = hcur; hcur = hnxt; hnxt = tmp;
    }
    // t16 = bf16(agg @ W1 + b1)   (+stats1)
    hipLaunchKernelGGL((k_mmx<IN_BF16, true>), dim3(ntiles), dim3(256), 0, stream,
                       a16, Wt16 + (size_t)(1 + l) * EMB * EMB, b1 + (size_t)l * EMB,
                       (const float*)nullptr, (const float*)nullptr,
                       (const float*)nullptr, 0.f, t16, stats1, N);
    // u16 = bf16(relu(bn1(t)) @ W2 + b2)   (BN fused, +stats2)
    hipLaunchKernelGGL((k_mmx<IN_BF16BN, true>), dim3(ntiles), dim3(256), 0, stream,
                       t16, Wt16 + (size_t)(1 + L + l) * EMB * EMB, b2 + (size_t)l * EMB,
                       stats1, g1 + (size_t)l * EMB, be1 + (size_t)l * EMB, invN,
                       u16, stats2, N);
  }
  // final: out32 = relu(bn2_{L-1}(u)) + h_{L-1}
  hipLaunchKernelGGL(k_bnres_last, dim3(1024), dim3(256), 0, stream,
                     u16, stats + (size_t)((L - 1) * 2 + 1) * 1024,
                     g_out + (size_t)(L - 1) * EMB, be_out + (size_t)(L - 1) * EMB,
                     hcur, (float*)d_out, invN, N * 16);
}

// Round 12
// 359.491 us; speedup vs baseline: 1.1789x; 1.1789x over previous
//
#include <hip/hip_runtime.h>
#include <stdint.h>

#define EMB 64
#define BN_EPS 1e-5f
#define BSH 8              // bucket = 256 consecutive dst nodes
#define CHUNK 4096         // edges per k_part chunk (== hist chunk)
#define TS 68              // fp32 LDS tile stride: 2-way max bank aliasing

typedef short bfrag __attribute__((ext_vector_type(8)));   // 8 bf16 = 4 VGPRs
typedef float f32x4 __attribute__((ext_vector_type(4)));

#define IN_F32    0
#define IN_BF16   1
#define IN_BF16BN 2

struct SMM {
  float tb[64 * TS];            // 17408 B
  float st[128];                // 512 B
  float scs[EMB], shs[EMB];     // 512 B
  unsigned short wb[4096];      // 8192 B (encoder weights, enc path only)
};

__device__ __forceinline__ unsigned short f2b(float x) {
  unsigned u = __float_as_uint(x);
  u += 0x7FFFu + ((u >> 16) & 1u);   // round-to-nearest-even
  return (unsigned short)(u >> 16);
}
__device__ __forceinline__ float b2f(unsigned short v) {
  return __uint_as_float(((unsigned)v) << 16);
}

// ---------------- 512-thr MFMA tile core (encoder only) --------------------
__device__ __forceinline__ void enc_tile(SMM& sm, int tile,
    const float* x, const float* aewf, const float* bias,
    unsigned short* out16, int N) {
  const int tid = threadIdx.x;       // 0..511
  const int lane = tid & 63;
  const int wv = tid >> 6;           // 0..7
  const int r = wv >> 1;             // row-tile 0..3
  const int c0 = (wv & 1) * 2;       // col-tile pair
  const int m = lane & 15;
  const int quad = lane >> 4;
  const int node0 = tile * 64;

  // self-convert encoder weights: wb[j*64+k] = bf16(ae_w[k][j])
#pragma unroll
  for (int it = 0; it < 8; it++) {
    int idx = it * 512 + tid;
    int j = idx >> 6, k = idx & 63;
    sm.wb[idx] = f2b(aewf[k * EMB + j]);
  }
  __syncthreads();

  bfrag a0 = {0, 0, 0, 0, 0, 0, 0, 0}, a1 = {0, 0, 0, 0, 0, 0, 0, 0};
  const int arow = node0 + r * 16 + m;
  if (arow < N) {
    const float* af = x + (size_t)arow * EMB + quad * 8;
#pragma unroll
    for (int j = 0; j < 8; j++) {
      a0[j] = (short)f2b(af[j]);
      a1[j] = (short)f2b(af[32 + j]);
    }
  }
  f32x4 zz[2];
#pragma unroll
  for (int cc = 0; cc < 2; cc++) {
    const int c = c0 + cc;
    const unsigned short* bb = &sm.wb[(c * 16 + m) * EMB + quad * 8];
    bfrag b0 = *(const bfrag*)bb;
    bfrag b1 = *(const bfrag*)(bb + 32);
    f32x4 z = {0.f, 0.f, 0.f, 0.f};
    z = __builtin_amdgcn_mfma_f32_16x16x32_bf16(a0, b0, z, 0, 0, 0);
    z = __builtin_amdgcn_mfma_f32_16x16x32_bf16(a1, b1, z, 0, 0, 0);
    zz[cc] = z;
  }
#pragma unroll
  for (int cc = 0; cc < 2; cc++) {
    const int c = c0 + cc;
    float bj = bias[c * 16 + m];
#pragma unroll
    for (int reg = 0; reg < 4; reg++) {
      int row = r * 16 + quad * 4 + reg;
      float v = (node0 + row < N) ? (zz[cc][reg] + bj) : 0.f;
      sm.tb[row * TS + c * 16 + m] = v;
    }
  }
  __syncthreads();
  ushort4* o4 = (ushort4*)(out16 + (size_t)node0 * EMB);
#pragma unroll
  for (int it = 0; it < 2; it++) {
    int flat4 = it * 512 + tid;
    int nsub = flat4 >> 4;
    int c4 = flat4 & 15;
    if (node0 + nsub < N) {
      const float* s4 = sm.tb + nsub * TS + c4 * 4;
      ushort4 o;
      o.x = f2b(s4[0]); o.y = f2b(s4[1]);
      o.z = f2b(s4[2]); o.w = f2b(s4[3]);
      o4[flat4] = o;
    }
  }
}

// ---- dispatch 1: encoder tiles + {W transpose, stats zero, hist chunks} ---
__global__ void __launch_bounds__(512) k_enc_prep(
        const float* __restrict__ x, const float* __restrict__ ae_w,
        const float* __restrict__ ae_b,
        const float* __restrict__ W1, const float* __restrict__ W2,
        unsigned short* __restrict__ Wt16, int* __restrict__ hist_part,
        float* __restrict__ stats, const int* __restrict__ ei,
        unsigned short* __restrict__ hb16,
        int E, int L, int nstats, int ntiles, int nchunks, int N) {
  __shared__ SMM sm;
  if ((int)blockIdx.x < ntiles) {
    enc_tile(sm, blockIdx.x, x, ae_w, ae_b, hb16, N);
    return;
  }
  const int pb = blockIdx.x - ntiles;   // chunk id 0..nchunks-1
  const int tid = threadIdx.x;
  int* lh = (int*)sm.tb;
  // W1/W2 -> transposed bf16 at Wt16[1+m]
  const int nw2 = 2 * L * EMB * EMB;
  for (int gid = pb * 512 + tid; gid < nw2; gid += nchunks * 512) {
    int mI = gid >> 12;
    int j = (gid >> 6) & 63;
    int k = gid & 63;
    const float* src = (mI < L) ? W1 + (size_t)mI * EMB * EMB
                                : W2 + (size_t)(mI - L) * EMB * EMB;
    Wt16[EMB * EMB + gid] = f2b(src[k * EMB + j]);
  }
  for (int i = pb * 512 + tid; i < nstats; i += nchunks * 512) stats[i] = 0.0f;
  // chunk-local histogram (matches k_part's chunk exactly)
  if (tid < 256) lh[tid] = 0;
  __syncthreads();
  const int c0 = pb * CHUNK;
  const int cend = min(c0 + CHUNK, E);
  for (int e = c0 + tid; e < cend; e += 512)
    atomicAdd(&lh[((unsigned)ei[E + e]) >> BSH], 1);
  __syncthreads();
  if (tid < 256) hist_part[pb * 256 + tid] = lh[tid];
}

// ---- phase 1: deterministic compact; chunk-prefix loops 8-deep unrolled ---
__global__ void __launch_bounds__(256) k_part(
        const int* __restrict__ ei, const float* __restrict__ ew,
        const int* __restrict__ hist_part, int* __restrict__ bbase,
        int2* __restrict__ eG, int E, int nchunks, int nb) {
  __shared__ int a[256], lbase[256], loff[256];
  const int t = threadIdx.x;
  const int c = blockIdx.x;
  // pre = edges of earlier chunks in bucket t; tot = all chunks
  int pre = 0, post = 0;
#pragma unroll 8
  for (int cc = 0; cc < c; cc++) pre += hist_part[cc * 256 + t];
#pragma unroll 8
  for (int cc = c; cc < nchunks; cc++) post += hist_part[cc * 256 + t];
  const int tot = pre + post;
  a[t] = tot;
  __syncthreads();
  for (int off = 1; off < 256; off <<= 1) {
    int x = (t >= off) ? a[t - off] : 0;
    __syncthreads();
    a[t] += x;
    __syncthreads();
  }
  int excl = a[t] - tot;
  lbase[t] = excl + pre;
  loff[t] = 0;
  if (c == 0 && t <= nb) bbase[t] = excl;   // bbase[nb] == E
  __syncthreads();
  const int c0 = c * CHUNK;
#pragma unroll 4
  for (int i = 0; i < 16; i++) {
    int e = c0 + i * 256 + t;
    if (e < E) {
      int d = ei[E + e];
      int g = ((unsigned)d) >> BSH;
      int pk = ei[e] | ((d & 255) << 24);
      int pos = lbase[g] + atomicAdd(&loff[g], 1);
      eG[pos] = make_int2(pk, __float_as_int(ew[e]));
    }
  }
}

// ---------------- phase 2: exact CSR inside each bucket --------------------
__global__ void __launch_bounds__(256) k_build(
        const int2* __restrict__ eG, const int* __restrict__ bbase,
        int* __restrict__ rowst, int* __restrict__ counts,
        int2* __restrict__ pairs, int N) {
  __shared__ int lcnt[256], a[256], lcur[256];
  const int t = threadIdx.x;
  const int b = blockIdx.x;
  const int e0 = bbase[b], e1 = bbase[b + 1];
  lcnt[t] = 0;
  __syncthreads();
  for (int i = e0 + t; i < e1; i += 256)
    atomicAdd(&lcnt[((unsigned)eG[i].x) >> 24], 1);
  __syncthreads();
  int v = lcnt[t];
  a[t] = v;
  __syncthreads();
  for (int off = 1; off < 256; off <<= 1) {
    int x = (t >= off) ? a[t - off] : 0;
    __syncthreads();
    a[t] += x;
    __syncthreads();
  }
  int excl = a[t] - v;
  lcur[t] = excl;
  int node = (b << BSH) + t;
  if (node < N) { rowst[node] = e0 + excl; counts[node] = v; }
  __syncthreads();
  for (int i = e0 + t; i < e1; i += 256) {
    int2 p = eG[i];
    int loc = ((unsigned)p.x) >> 24;
    int pos = e0 + atomicAdd(&lcur[loc], 1);
    pairs[pos] = make_int2(p.x & 0x00FFFFFF, p.y);
  }
}

// ---- layer-0 aggregation: dword-packed gather, 2 nodes interleaved --------
__global__ void k_agg(const unsigned short* __restrict__ hb,
                      const int* __restrict__ rowst,
                      const int* __restrict__ counts, const int2* __restrict__ pairs,
                      unsigned short* __restrict__ out16, int N) {
  const int lane = threadIdx.x & 63;
  const int half = lane >> 5;          // 0: even slots, 1: odd slots
  const int col = lane & 31;           // dword col -> features 2col, 2col+1
  int wave = (blockIdx.x * blockDim.x + threadIdx.x) >> 6;
  const int nwaves = (gridDim.x * blockDim.x) >> 6;
  for (int nA = wave; nA < N; nA += 2 * nwaves) {
    const int nB = nA + nwaves;
    const int uA = __builtin_amdgcn_readfirstlane(nA);
    const int uB = __builtin_amdgcn_readfirstlane(nB);
    const bool hasB = uB < N;
    int sA = rowst[uA], eA = sA + counts[uA];
    int sB = 0, eB = 0;
    if (hasB) { sB = rowst[uB]; eB = sB + counts[uB]; }
    float a0A[4] = {0, 0, 0, 0}, a1A[4] = {0, 0, 0, 0};
    float a0B[4] = {0, 0, 0, 0}, a1B[4] = {0, 0, 0, 0};
    for (int xA = sA, xB = sB; (xA < eA) | (xB < eB); xA += 8, xB += 8) {
      int2 pA[8], pB[8];
#pragma unroll
      for (int k = 0; k < 8; k++) {
        int ia = xA + k;
        pA[k] = pairs[ia < eA ? ia : 0];
      }
#pragma unroll
      for (int k = 0; k < 8; k++) {
        int ib = xB + k;
        pB[k] = pairs[ib < eB ? ib : 0];
      }
#pragma unroll
      for (int j = 0; j < 4; j++) {
        int2 pp = half ? pA[2 * j + 1] : pA[2 * j];
        bool ok = (xA + 2 * j + half) < eA;
        float w = ok ? __int_as_float(pp.y) : 0.f;
        unsigned v = *((const unsigned*)(hb + (size_t)pp.x * EMB) + col);
        a0A[j] = fmaf(w, b2f((unsigned short)(v & 0xFFFFu)), a0A[j]);
        a1A[j] = fmaf(w, b2f((unsigned short)(v >> 16)), a1A[j]);
      }
#pragma unroll
      for (int j = 0; j < 4; j++) {
        int2 pp = half ? pB[2 * j + 1] : pB[2 * j];
        bool ok = (xB + 2 * j + half) < eB;
        float w = ok ? __int_as_float(pp.y) : 0.f;
        unsigned v = *((const unsigned*)(hb + (size_t)pp.x * EMB) + col);
        a0B[j] = fmaf(w, b2f((unsigned short)(v & 0xFFFFu)), a0B[j]);
        a1B[j] = fmaf(w, b2f((unsigned short)(v >> 16)), a1B[j]);
      }
    }
    {
      float s0 = (a0A[0] + a0A[1]) + (a0A[2] + a0A[3]);
      float s1 = (a1A[0] + a1A[1]) + (a1A[2] + a1A[3]);
      s0 += __shfl_xor(s0, 32);
      s1 += __shfl_xor(s1, 32);
      float v0 = __shfl(s0, lane >> 1);
      float v1 = __shfl(s1, lane >> 1);
      float sum = ((lane & 1) ? v1 : v0) + b2f(hb[(size_t)uA * EMB + lane]);
      out16[(size_t)uA * EMB + lane] = f2b(sum);
    }
    if (hasB) {
      float s0 = (a0B[0] + a0B[1]) + (a0B[2] + a0B[3]);
      float s1 = (a1B[0] + a1B[1]) + (a1B[2] + a1B[3]);
      s0 += __shfl_xor(s0, 32);
      s1 += __shfl_xor(s1, 32);
      float v0 = __shfl(s0, lane >> 1);
      float v1 = __shfl(s1, lane >> 1);
      float sum = ((lane & 1) ? v1 : v0) + b2f(hb[(size_t)uB * EMB + lane]);
      out16[(size_t)uB * EMB + lane] = f2b(sum);
    }
  }
}

// ---- layers 1..: fused bnres + aggregation (lazy BN2, ping-pong h) -------
// Gather recomputes h_l[src] = relu(bn2(u[src])) + hold[src] per edge
// (2 dword loads/edge, 8-deep per-lane load pipeline). Each wave also
// materializes h_l for its own nodes into hnew (race-free).
__global__ void k_aggbn(const unsigned short* __restrict__ u16,
                        const unsigned short* __restrict__ hold,
                        const float* __restrict__ st,
                        const float* __restrict__ g, const float* __restrict__ be,
                        const int* __restrict__ rowst,
                        const int* __restrict__ counts,
                        const int2* __restrict__ pairs,
                        unsigned short* __restrict__ hnew,
                        unsigned short* __restrict__ out16,
                        float invN, int N) {
  __shared__ float scs[EMB], shs[EMB];
  const int tid = threadIdx.x;
  if (tid < EMB) {
    float s1 = 0.f, s2 = 0.f;
#pragma unroll
    for (int k = 0; k < 8; k++) {
      s1 += st[k * 128 + tid];
      s2 += st[k * 128 + 64 + tid];
    }
    float mu = s1 * invN;
    float va = fmaf(s2, invN, -mu * mu);
    float rs = rsqrtf(va + BN_EPS);
    float sc = rs * g[tid];
    scs[tid] = sc;
    shs[tid] = fmaf(-mu, sc, be[tid]);
  }
  __syncthreads();
  const int lane = tid & 63;
  const int half = lane >> 5;
  const int col = lane & 31;
  const float sc0 = scs[2 * col], sc1 = scs[2 * col + 1];
  const float sh0 = shs[2 * col], sh1 = shs[2 * col + 1];
  const float scl = scs[lane], shl = shs[lane];
  int wave = (blockIdx.x * blockDim.x + tid) >> 6;
  const int nwaves = (gridDim.x * blockDim.x) >> 6;
  for (int n = wave; n < N; n += nwaves) {
    const int un = __builtin_amdgcn_readfirstlane(n);
    const int s = rowst[un];
    const int e = s + counts[un];
    // self row: h_l[n] at feature `lane`
    float uu = b2f(u16[(size_t)un * EMB + lane]);
    float hh = b2f(hold[(size_t)un * EMB + lane]);
    float hn = fmaxf(0.f, fmaf(uu, scl, shl)) + hh;
    float a0[4] = {0, 0, 0, 0}, a1[4] = {0, 0, 0, 0};
    for (int x = s; x < e; x += 8) {
      int2 pp[8];
#pragma unroll
      for (int k = 0; k < 8; k++) {
        int i = x + k;
        pp[k] = pairs[i < e ? i : 0];
      }
#pragma unroll
      for (int j = 0; j < 4; j++) {
        int2 p = half ? pp[2 * j + 1] : pp[2 * j];
        bool ok = (x + 2 * j + half) < e;
        float w = ok ? __int_as_float(p.y) : 0.f;
        const size_t base = (size_t)p.x * EMB;
        unsigned vu = *((const unsigned*)(u16 + base) + col);
        unsigned vh = *((const unsigned*)(hold + base) + col);
        float h0 = fmaxf(0.f, fmaf(b2f((unsigned short)(vu & 0xFFFFu)), sc0, sh0))
                   + b2f((unsigned short)(vh & 0xFFFFu));
        float h1 = fmaxf(0.f, fmaf(b2f((unsigned short)(vu >> 16)), sc1, sh1))
                   + b2f((unsigned short)(vh >> 16));
        a0[j] = fmaf(w, h0, a0[j]);
        a1[j] = fmaf(w, h1, a1[j]);
      }
    }
    float s0 = (a0[0] + a0[1]) + (a0[2] + a0[3]);
    float s1 = (a1[0] + a1[1]) + (a1[2] + a1[3]);
    s0 += __shfl_xor(s0, 32);
    s1 += __shfl_xor(s1, 32);
    float v0 = __shfl(s0, lane >> 1);
    float v1 = __shfl(s1, lane >> 1);
    float sum = ((lane & 1) ? v1 : v0) + hn;
    out16[(size_t)un * EMB + lane] = f2b(sum);
    hnew[(size_t)un * EMB + lane] = f2b(hn);
  }
}

// ---------------- MFMA matmul: block = 64-node tile, 4 waves ---------------
template <int INMODE, bool DO_STATS>
__global__ void __launch_bounds__(256) k_mmx(
        const void* __restrict__ in_v, const unsigned short* __restrict__ Wt,
        const float* __restrict__ bias, const float* __restrict__ stats,
        const float* __restrict__ g, const float* __restrict__ be, float invN,
        unsigned short* __restrict__ out16, float* __restrict__ st_out, int N) {
  __shared__ float tb[64 * TS];
  __shared__ float st_part[128];
  __shared__ float scs[EMB], shs[EMB];
  const int tid = threadIdx.x;
  const int lane = tid & 63;
  const int wv = tid >> 6;
  const int node0 = blockIdx.x * 64;
  const int m = lane & 15;
  const int quad = lane >> 4;

  if (DO_STATS && tid < 128) st_part[tid] = 0.f;
  if (INMODE == IN_BF16BN) {
    if (tid < EMB) {
      float s1 = 0.f, s2 = 0.f;
#pragma unroll
      for (int k = 0; k < 8; k++) {
        s1 += stats[k * 128 + tid];
        s2 += stats[k * 128 + 64 + tid];
      }
      float mm = s1 * invN;
      float va = fmaf(s2, invN, -mm * mm);
      float rs = rsqrtf(va + BN_EPS);
      float sc = rs * g[tid];
      scs[tid] = sc;
      shs[tid] = fmaf(-mm, sc, be[tid]);
    }
    __syncthreads();
  }

  const int arow = node0 + wv * 16 + m;
  bfrag a0 = {0, 0, 0, 0, 0, 0, 0, 0}, a1 = {0, 0, 0, 0, 0, 0, 0, 0};
  if (arow < N) {
    if (INMODE == IN_BF16) {
      const unsigned short* ab =
          (const unsigned short*)in_v + (size_t)arow * EMB + quad * 8;
      a0 = *(const bfrag*)ab;
      a1 = *(const bfrag*)(ab + 32);
    } else if (INMODE == IN_BF16BN) {
      const unsigned short* ab =
          (const unsigned short*)in_v + (size_t)arow * EMB + quad * 8;
      bfrag r0 = *(const bfrag*)ab;
      bfrag r1 = *(const bfrag*)(ab + 32);
#pragma unroll
      for (int j = 0; j < 8; j++) {
        int k0 = quad * 8 + j;
        float v0 = b2f((unsigned short)r0[j]);
        float v1 = b2f((unsigned short)r1[j]);
        v0 = fmaxf(0.f, fmaf(v0, scs[k0], shs[k0]));
        v1 = fmaxf(0.f, fmaf(v1, scs[k0 + 32], shs[k0 + 32]));
        a0[j] = (short)f2b(v0);
        a1[j] = (short)f2b(v1);
      }
    }
  }

  const unsigned short* bb = Wt + (size_t)m * EMB + quad * 8;
  f32x4 acc[4];
#pragma unroll
  for (int c = 0; c < 4; c++) {
    bfrag b0 = *(const bfrag*)(bb + c * 16 * EMB);
    bfrag b1 = *(const bfrag*)(bb + c * 16 * EMB + 32);
    f32x4 z = {0.f, 0.f, 0.f, 0.f};
    z = __builtin_amdgcn_mfma_f32_16x16x32_bf16(a0, b0, z, 0, 0, 0);
    z = __builtin_amdgcn_mfma_f32_16x16x32_bf16(a1, b1, z, 0, 0, 0);
    acc[c] = z;
  }

#pragma unroll
  for (int c = 0; c < 4; c++) {
    float bj = bias[c * 16 + m];
#pragma unroll
    for (int r = 0; r < 4; r++) {
      int row = wv * 16 + quad * 4 + r;
      float v = (node0 + row < N) ? (acc[c][r] + bj) : 0.f;
      tb[row * TS + c * 16 + m] = v;
    }
  }
  __syncthreads();

  if (DO_STATS) {
    float ssum = 0.f, ssq = 0.f;
#pragma unroll
    for (int i = 0; i < 16; i++) {
      float v = tb[(wv * 16 + i) * TS + lane];
      ssum += v;
      ssq = fmaf(v, v, ssq);
    }
    atomicAdd(&st_part[lane], ssum);
    atomicAdd(&st_part[64 + lane], ssq);
  }

  ushort4* o4 = (ushort4*)(out16 + (size_t)node0 * EMB);
#pragma unroll
  for (int it = 0; it < 4; it++) {
    int flat4 = it * 256 + tid;
    int nsub = flat4 >> 4;
    int c4 = flat4 & 15;
    if (node0 + nsub < N) {
      const float* s4 = tb + nsub * TS + c4 * 4;
      ushort4 o;
      o.x = f2b(s4[0]); o.y = f2b(s4[1]);
      o.z = f2b(s4[2]); o.w = f2b(s4[3]);
      o4[flat4] = o;
    }
  }

  if (DO_STATS) {
    __syncthreads();
    if (tid < 128)
      atomicAdd(&st_out[((unsigned)blockIdx.x & 7u) * 128 + tid], st_part[tid]);
  }
}

// ---------------- final BN + relu + residual -> fp32 out -------------------
__global__ void k_bnres_last(const unsigned short* __restrict__ u16,
                             const float* __restrict__ st,
                             const float* __restrict__ g,
                             const float* __restrict__ be,
                             const unsigned short* __restrict__ hb16,
                             float* __restrict__ out32,
                             float invN, int total4) {
  __shared__ float scs[EMB], shs[EMB];
  const int tid = threadIdx.x;
  if (tid < EMB) {
    float s1 = 0.f, s2 = 0.f;
#pragma unroll
    for (int k = 0; k < 8; k++) {
      s1 += st[k * 128 + tid];
      s2 += st[k * 128 + 64 + tid];
    }
    float mm = s1 * invN;
    float va = fmaf(s2, invN, -mm * mm);
    float rs = rsqrtf(va + BN_EPS);
    float sc = rs * g[tid];
    scs[tid] = sc;
    shs[tid] = fmaf(-mm, sc, be[tid]);
  }
  __syncthreads();
  int stride = gridDim.x * blockDim.x;
  for (int i4 = blockIdx.x * blockDim.x + tid; i4 < total4; i4 += stride) {
    int c4 = i4 & 15;
    ushort4 uv = ((const ushort4*)u16)[i4];
    ushort4 hv = ((const ushort4*)hb16)[i4];
    float4 scv = *(const float4*)&scs[c4 * 4];
    float4 shv = *(const float4*)&shs[c4 * 4];
    float4 o;
    o.x = fmaxf(0.f, fmaf(b2f(uv.x), scv.x, shv.x)) + b2f(hv.x);
    o.y = fmaxf(0.f, fmaf(b2f(uv.y), scv.y, shv.y)) + b2f(hv.y);
    o.z = fmaxf(0.f, fmaf(b2f(uv.z), scv.z, shv.z)) + b2f(hv.z);
    o.w = fmaxf(0.f, fmaf(b2f(uv.w), scv.w, shv.w)) + b2f(hv.w);
    ((float4*)out32)[i4] = o;
  }
}

// ---------------- launcher ----------------
extern "C" void kernel_launch(void* const* d_in, const int* in_sizes, int n_in,
                              void* d_out, int out_size, void* d_ws, size_t ws_size,
                              hipStream_t stream) {
  const float* x     = (const float*)d_in[0];
  const int*   ei    = (const int*)d_in[1];
  const float* ew    = (const float*)d_in[3];
  const float* ae_w  = (const float*)d_in[4];
  const float* ae_b  = (const float*)d_in[5];
  const float* W1    = (const float*)d_in[6];
  const float* b1    = (const float*)d_in[7];
  const float* g1    = (const float*)d_in[8];
  const float* be1   = (const float*)d_in[9];
  const float* W2    = (const float*)d_in[10];
  const float* b2    = (const float*)d_in[11];
  const float* g_out = (const float*)d_in[12];
  const float* be_out= (const float*)d_in[13];

  const int N = in_sizes[0] / EMB;
  const int E = in_sizes[3];
  const int L = in_sizes[6] / (EMB * EMB);
  const float invN = 1.0f / (float)N;
  const int NBUCK = (N + 255) >> BSH;
  const int nchunks = (E + CHUNK - 1) / CHUNK;

  uintptr_t p = (uintptr_t)d_ws;
  auto alloc = [&](size_t bytes) -> void* {
    p = (p + 255) & ~(uintptr_t)255;
    void* r = (void*)p;
    p += bytes;
    return r;
  };
  unsigned short* hbA  = (unsigned short*)alloc((size_t)N * EMB * 2); // h ping
  unsigned short* hbB  = (unsigned short*)alloc((size_t)N * EMB * 2); // h pong
  unsigned short* a16  = (unsigned short*)alloc((size_t)N * EMB * 2); // agg out
  unsigned short* t16  = (unsigned short*)alloc((size_t)N * EMB * 2); // t
  unsigned short* u16  = (unsigned short*)alloc((size_t)N * EMB * 2); // u (mm2)
  unsigned short* Wt16 = (unsigned short*)alloc((size_t)(1 + 2 * L) * EMB * EMB * 2);
  int*   counts= (int*)alloc((size_t)N * 4);
  int*   rowst = (int*)alloc((size_t)N * 4);
  int*   hist_part = (int*)alloc((size_t)nchunks * 256 * 4);
  int*   bbase = (int*)alloc(257 * 4);
  int2*  pairs = (int2*)alloc((size_t)E * 8);
  int2*  eG    = (int2*)alloc((size_t)E * 8);
  float* stats = (float*)alloc((size_t)L * 2 * 8 * 128 * 4);
  (void)ws_size; (void)n_in; (void)out_size;

  const int ntiles = (N + 63) / 64;
  const int nstats = L * 2 * 8 * 128;

  // dispatch 1: encoder tiles + {W transpose, stats zero, chunked hist}
  hipLaunchKernelGGL(k_enc_prep, dim3(ntiles + nchunks), dim3(512), 0, stream,
                     x, ae_w, ae_b, W1, W2, Wt16, hist_part, stats, ei,
                     hbA, E, L, nstats, ntiles, nchunks, N);
  // deterministic compact (writes bbase), then exact per-bucket CSR
  hipLaunchKernelGGL(k_part, dim3(nchunks), dim3(256), 0, stream,
                     ei, ew, hist_part, bbase, eG, E, nchunks, NBUCK);
  hipLaunchKernelGGL(k_build, dim3(NBUCK), dim3(256), 0, stream,
                     eG, bbase, rowst, counts, pairs, N);

  unsigned short* hcur = hbA;
  unsigned short* hnxt = hbB;
  for (int l = 0; l < L; l++) {
    float* stats1 = stats + (size_t)(l * 2 + 0) * 1024;
    float* stats2 = stats + (size_t)(l * 2 + 1) * 1024;

    if (l == 0) {
      hipLaunchKernelGGL(k_agg, dim3(2048), dim3(256), 0, stream,
                         hcur, rowst, counts, pairs, a16, N);
    } else {
      float* stats2p = stats + (size_t)((l - 1) * 2 + 1) * 1024;
      hipLaunchKernelGGL(k_aggbn, dim3(2048), dim3(256), 0, stream,
                         u16, hcur, stats2p, g_out + (size_t)(l - 1) * EMB,
                         be_out + (size_t)(l - 1) * EMB, rowst, counts, pairs,
                         hnxt, a16, invN, N);
      unsigned short* tmp = hcur; hcur = hnxt; hnxt = tmp;
    }
    // t16 = bf16(agg @ W1 + b1)   (+stats1)
    hipLaunchKernelGGL((k_mmx<IN_BF16, true>), dim3(ntiles), dim3(256), 0, stream,
                       a16, Wt16 + (size_t)(1 + l) * EMB * EMB, b1 + (size_t)l * EMB,
                       (const float*)nullptr, (const float*)nullptr,
                       (const float*)nullptr, 0.f, t16, stats1, N);
    // u16 = bf16(relu(bn1(t)) @ W2 + b2)   (BN fused, +stats2)
    hipLaunchKernelGGL((k_mmx<IN_BF16BN, true>), dim3(ntiles), dim3(256), 0, stream,
                       t16, Wt16 + (size_t)(1 + L + l) * EMB * EMB, b2 + (size_t)l * EMB,
                       stats1, g1 + (size_t)l * EMB, be1 + (size_t)l * EMB, invN,
                       u16, stats2, N);
  }
  // final: out32 = relu(bn2_{L-1}(u)) + h_{L-1}
  hipLaunchKernelGGL(k_bnres_last, dim3(1024), dim3(256), 0, stream,
                     u16, stats + (size_t)((L - 1) * 2 + 1) * 1024,
                     g_out + (size_t)(L - 1) * EMB, be_out + (size_t)(L - 1) * EMB,
                     hcur, (float*)d_out, invN, N * 16);
}